// Round 1
// baseline (494.786 us; speedup 1.0000x reference)
//
#include <hip/hip_runtime.h>

// Problem constants (from reference)
#define IN_C   32
#define CH     35          // IN_C + 3
#define HID    8
#define P_CNT  369         // CH*HID + HID + HID*HID + HID + HID*1 + 1
#define NPROP  128
#define NALL   100000
#define PSTRIDE 372        // per-proposal LDS stride, padded to multiple of 4 floats (16B align)

// ---------------- Kernel A: params = prop_feats @ W_dyn + b_dyn ----------------
// params layout: [p][j], j in [0,369), row-major, stored flat in d_ws.
__global__ void params_kernel(const float* __restrict__ prop,
                              const float* __restrict__ W,
                              const float* __restrict__ b,
                              float* __restrict__ params) {
    int i = blockIdx.x * blockDim.x + threadIdx.x;
    if (i >= NPROP * P_CNT) return;
    int p = i / P_CNT;
    int j = i - p * P_CNT;
    float acc = b[j];
    const float* pr = prop + p * IN_C;
    #pragma unroll
    for (int c = 0; c < IN_C; ++c)
        acc = fmaf(pr[c], W[c * P_CNT + j], acc);   // W column j, coalesced across lanes
    params[i] = acc;
}

// ---------------- Kernel B: fused 3-layer MLP over (p, a) ----------------
// One thread per feature row a. Each block: 64 a's, loops over 64 p's
// (8 groups of 8 p's staged in LDS). grid.y splits p-range in two.
#define PGRP 8

__global__ __launch_bounds__(64, 4) void mlp_kernel(
        const float* __restrict__ all_features,
        const float* __restrict__ params,
        float* __restrict__ out) {
    __shared__ float ps[PGRP * PSTRIDE];

    const int tid = threadIdx.x;
    const int a = blockIdx.x * 64 + tid;
    const int pbase0 = blockIdx.y * 64;
    const bool valid = a < NALL;

    // Load this thread's feature row into registers (one-time, reused for 64 p's)
    float af[CH];
    if (valid) {
        const float* row = all_features + (long)a * CH;
        #pragma unroll
        for (int c = 0; c < CH; ++c) af[c] = row[c];
    } else {
        #pragma unroll
        for (int c = 0; c < CH; ++c) af[c] = 0.f;
    }

    for (int g = 0; g < 64 / PGRP; ++g) {
        const int pbase = pbase0 + g * PGRP;
        __syncthreads();   // protect LDS from previous iteration's readers
        // Stage PGRP proposals' params into LDS (padded stride for float4 access)
        #pragma unroll
        for (int lp = 0; lp < PGRP; ++lp) {
            const float* src = params + (long)(pbase + lp) * P_CNT;
            for (int i = tid; i < P_CNT; i += 64)
                ps[lp * PSTRIDE + i] = src[i];
        }
        __syncthreads();

        if (valid) {
            #pragma unroll 1
            for (int lp = 0; lp < PGRP; ++lp) {
                const float4* w4 = (const float4*)(ps + lp * PSTRIDE);
                // float4 index map within a proposal's 369 floats:
                // w1[c] -> f4 {2c, 2c+1} (c<35) | b1 -> 70,71 | w2[h] -> 72+2h,73+2h
                // b2 -> 88,89 | w3 -> 90,91 | b3 -> float 368
                float acc[8];
                {
                    float4 b0 = w4[70], b1 = w4[71];
                    acc[0]=b0.x; acc[1]=b0.y; acc[2]=b0.z; acc[3]=b0.w;
                    acc[4]=b1.x; acc[5]=b1.y; acc[6]=b1.z; acc[7]=b1.w;
                }
                #pragma unroll
                for (int c = 0; c < CH; ++c) {
                    float x = af[c];
                    float4 w0 = w4[2*c], w1 = w4[2*c+1];
                    acc[0] = fmaf(x, w0.x, acc[0]);
                    acc[1] = fmaf(x, w0.y, acc[1]);
                    acc[2] = fmaf(x, w0.z, acc[2]);
                    acc[3] = fmaf(x, w0.w, acc[3]);
                    acc[4] = fmaf(x, w1.x, acc[4]);
                    acc[5] = fmaf(x, w1.y, acc[5]);
                    acc[6] = fmaf(x, w1.z, acc[6]);
                    acc[7] = fmaf(x, w1.w, acc[7]);
                }
                #pragma unroll
                for (int h = 0; h < 8; ++h) acc[h] = fmaxf(acc[h], 0.f);

                float h2[8];
                {
                    float4 b0 = w4[88], b1 = w4[89];
                    h2[0]=b0.x; h2[1]=b0.y; h2[2]=b0.z; h2[3]=b0.w;
                    h2[4]=b1.x; h2[5]=b1.y; h2[6]=b1.z; h2[7]=b1.w;
                }
                #pragma unroll
                for (int h = 0; h < 8; ++h) {
                    float x = acc[h];
                    float4 u0 = w4[72 + 2*h], u1 = w4[73 + 2*h];
                    h2[0] = fmaf(x, u0.x, h2[0]);
                    h2[1] = fmaf(x, u0.y, h2[1]);
                    h2[2] = fmaf(x, u0.z, h2[2]);
                    h2[3] = fmaf(x, u0.w, h2[3]);
                    h2[4] = fmaf(x, u1.x, h2[4]);
                    h2[5] = fmaf(x, u1.y, h2[5]);
                    h2[6] = fmaf(x, u1.z, h2[6]);
                    h2[7] = fmaf(x, u1.w, h2[7]);
                }
                #pragma unroll
                for (int h = 0; h < 8; ++h) h2[h] = fmaxf(h2[h], 0.f);

                float o = ps[lp * PSTRIDE + 368];
                {
                    float4 v0 = w4[90], v1 = w4[91];
                    o = fmaf(h2[0], v0.x, o);
                    o = fmaf(h2[1], v0.y, o);
                    o = fmaf(h2[2], v0.z, o);
                    o = fmaf(h2[3], v0.w, o);
                    o = fmaf(h2[4], v1.x, o);
                    o = fmaf(h2[5], v1.y, o);
                    o = fmaf(h2[6], v1.z, o);
                    o = fmaf(h2[7], v1.w, o);
                }
                out[(long)(pbase + lp) * NALL + a] = o;  // coalesced along a
            }
        }
    }
}

extern "C" void kernel_launch(void* const* d_in, const int* in_sizes, int n_in,
                              void* d_out, int out_size, void* d_ws, size_t ws_size,
                              hipStream_t stream) {
    const float* prop = (const float*)d_in[0];   // (128, 32)
    const float* allf = (const float*)d_in[1];   // (100000, 35)
    const float* W    = (const float*)d_in[2];   // (32, 369)
    const float* b    = (const float*)d_in[3];   // (369,)
    float* out    = (float*)d_out;               // (128, 100000, 1) flat
    float* params = (float*)d_ws;                // 128*369 floats = 189 KB scratch

    // Kernel A: 47232 outputs
    params_kernel<<<(NPROP * P_CNT + 255) / 256, 256, 0, stream>>>(prop, W, b, params);

    // Kernel B: 1563 a-blocks x 2 p-halves
    dim3 grid((NALL + 63) / 64, 2);
    mlp_kernel<<<grid, 64, 0, stream>>>(allf, params, out);
}

// Round 2
// 173.454 us; speedup vs baseline: 2.8525x; 2.8525x over previous
//
#include <hip/hip_runtime.h>

#define IN_C  32
#define CH    35
#define P_CNT 369
#define NPAIR 64
#define NALL  100000
#define NTILE 6250          // NALL / 16 exactly

// param offsets within a proposal's 369 floats
#define OW1 0               // w1[c][h] = c*8 + h   (c < 35)
#define OB1 280
#define OW2 288             // w2[h][k] = 288 + h*8 + k
#define OB2 352
#define OW3 360
#define OB3 368

// d_ws byte offsets (total 549,888 B)
#define WS_W1F 0            // ushort [64 pair][2 kh][64 lane][8]   131072 B
#define WS_W2F 131072       // ushort [64][64 lane][4]              32768 B
#define WS_B1F 163840       // float  [64][64 lane][4]              65536 B
#define WS_B2F 229376       // float  [64][64 lane][4]              65536 B
#define WS_W3F 294912       // float  [64][64 lane][4]              65536 B
#define WS_B3F 360448       // float  [64][2]                       512 B
#define WS_PRM 360960       // float  [128][369]                    188928 B

typedef short  bf16x8 __attribute__((ext_vector_type(8)));
typedef short  bf16x4 __attribute__((ext_vector_type(4)));
typedef float  f32x4  __attribute__((ext_vector_type(4)));

static __device__ inline unsigned short f2bf(float x) {
    union { float f; unsigned u; } v; v.f = x;
    unsigned r = v.u + 0x7FFFu + ((v.u >> 16) & 1u);   // round-to-nearest-even
    return (unsigned short)(r >> 16);
}

// ---------------- Prep: compute params for one pair (2 proposals) and pack
// ---------------- MFMA fragments lane-exactly. One 64-thread wave per pair.
__global__ __launch_bounds__(64) void prep_kernel(
        const float* __restrict__ prop,   // (128, 32)
        const float* __restrict__ W,      // (32, 369)
        const float* __restrict__ b,      // (369,)
        char* __restrict__ ws) {
    const int pp   = blockIdx.x;          // pair index 0..63
    const int lane = threadIdx.x;
    __shared__ float P[2][P_CNT];

    float* prm = (float*)(ws + WS_PRM);

    // params[2p..2p+1][:] = prop @ W + b   (738 dot products of length 32)
    for (int idx = lane; idx < 2 * P_CNT; idx += 64) {
        const int pl = (idx >= P_CNT) ? 1 : 0;
        const int j  = idx - pl * P_CNT;
        const float* pr = prop + (size_t)(2 * pp + pl) * IN_C;
        float acc = b[j];
        #pragma unroll
        for (int c = 0; c < IN_C; ++c)
            acc = fmaf(pr[c], W[(size_t)c * P_CNT + j], acc);
        P[pl][j] = acc;
        prm[(size_t)(2 * pp + pl) * P_CNT + j] = acc;   // plain copy (fallback path)
    }
    __syncthreads();

    const int g   = lane >> 4;            // lane group 0..3
    const int m   = lane & 15;            // M-row / N-col index within tile

    // W1F: A-fragment of 16x16x32 MFMA.  A[m = h-packed][k = c], lane: row=m, k=8g+j
    {
        unsigned short* w1f = (unsigned short*)(ws + WS_W1F);
        const int pl = m >> 3, h = m & 7;
        #pragma unroll
        for (int kh = 0; kh < 2; ++kh) {
            #pragma unroll
            for (int j = 0; j < 8; ++j) {
                const int c = kh * 32 + g * 8 + j;
                const float v = (c < CH) ? P[pl][OW1 + c * 8 + h] : 0.f;
                w1f[((size_t)(pp * 2 + kh) * 64 + lane) * 8 + j] = f2bf(v);
            }
        }
    }
    // B1F: C-init for layer1 = b1[row], row = 4g + r (h-packed)
    {
        float* b1f = (float*)(ws + WS_B1F);
        #pragma unroll
        for (int r = 0; r < 4; ++r) {
            const int row = g * 4 + r;
            b1f[((size_t)pp * 64 + lane) * 4 + r] = P[row >> 3][OB1 + (row & 7)];
        }
    }
    // W2F: A-fragment of 16x16x16 MFMA, block-diagonal packed w2.
    // A2[m = j-packed][k = h-packed]; lane: row = m = lane&15, k = 4g + r
    {
        unsigned short* w2f = (unsigned short*)(ws + WS_W2F);
        const int plj = m >> 3, jj = m & 7;
        #pragma unroll
        for (int r = 0; r < 4; ++r) {
            const int colh = g * 4 + r;
            const int ph = colh >> 3, h = colh & 7;
            const float v = (ph == plj) ? P[plj][OW2 + h * 8 + jj] : 0.f;
            w2f[((size_t)pp * 64 + lane) * 4 + r] = f2bf(v);
        }
    }
    // B2F: C-init for layer2 = b2[row], row = 4g + r (j-packed)
    // W3F: w3[row] per lane for the layer3 dot
    {
        float* b2f = (float*)(ws + WS_B2F);
        float* w3f = (float*)(ws + WS_W3F);
        #pragma unroll
        for (int r = 0; r < 4; ++r) {
            const int row = g * 4 + r;
            b2f[((size_t)pp * 64 + lane) * 4 + r] = P[row >> 3][OB2 + (row & 7)];
            w3f[((size_t)pp * 64 + lane) * 4 + r] = P[row >> 3][OW3 + (row & 7)];
        }
    }
    if (lane < 2) ((float*)(ws + WS_B3F))[pp * 2 + lane] = P[lane][OB3];
}

// ---------------- Main: one wave per 16-row feature tile, loops 32 pairs.
__global__ __launch_bounds__(256) void mlp_kernel(
        const float* __restrict__ allf,   // (100000, 35)
        const char* __restrict__ ws,
        float* __restrict__ out) {        // (128, 100000)
    const int lane = threadIdx.x & 63;
    const int wave = threadIdx.x >> 6;
    const int tile = blockIdx.x * 4 + wave;
    if (tile >= NTILE) return;
    const int abase = tile * 16;
    const int g   = lane >> 4;
    const int col = lane & 15;

    // Feature B-fragments (16x16x32): B[k = c][n = a]; lane: col=a, k = 8g+j.
    // Built once, reused for all pairs.
    const float* fr = allf + (size_t)(abase + col) * CH;
    bf16x8 bf0, bf1;
    #pragma unroll
    for (int j = 0; j < 8; ++j) {
        bf0[j] = (short)f2bf(fr[g * 8 + j]);                 // c = 0..31, all < 35
        const int c1 = 32 + g * 8 + j;
        bf1[j] = (short)(c1 < CH ? f2bf(fr[c1]) : (unsigned short)0);
    }

    const bf16x8* w1f = (const bf16x8*)(ws + WS_W1F);
    const bf16x4* w2f = (const bf16x4*)(ws + WS_W2F);
    const f32x4*  b1f = (const f32x4*)(ws + WS_B1F);
    const f32x4*  b2f = (const f32x4*)(ws + WS_B2F);
    const f32x4*  w3f = (const f32x4*)(ws + WS_W3F);
    const float*  b3f = (const float*)(ws + WS_B3F);
#if !__has_builtin(__builtin_amdgcn_mfma_f32_16x16x16bf16_1k)
    const float*  prm = (const float*)(ws + WS_PRM);
#endif

    const int ppbase = blockIdx.y * 32;
    for (int i = 0; i < 32; ++i) {
        const int pp = ppbase + i;

        // ---- layer 1: C1[h-packed, a] = w1^T @ feat^T + b1
        f32x4 c1 = b1f[pp * 64 + lane];
        c1 = __builtin_amdgcn_mfma_f32_16x16x32_bf16(w1f[(pp * 2 + 0) * 64 + lane], bf0, c1, 0, 0, 0);
        c1 = __builtin_amdgcn_mfma_f32_16x16x32_bf16(w1f[(pp * 2 + 1) * 64 + lane], bf1, c1, 0, 0, 0);

#if __has_builtin(__builtin_amdgcn_mfma_f32_16x16x16bf16_1k)
        // ---- layer 2: C1's output layout IS the 16x16x16 B-fragment layout.
        bf16x4 pb;
        #pragma unroll
        for (int r = 0; r < 4; ++r) pb[r] = (short)f2bf(fmaxf(c1[r], 0.f));
        f32x4 c2 = b2f[pp * 64 + lane];
        c2 = __builtin_amdgcn_mfma_f32_16x16x16bf16_1k(w2f[pp * 64 + lane], pb, c2, 0, 0, 0);

        // ---- layer 3: per-lane 4-row partial dot, combine with partner (xor 16)
        const f32x4 w3v = w3f[pp * 64 + lane];
        float s = 0.f;
        #pragma unroll
        for (int r = 0; r < 4; ++r) s = fmaf(fmaxf(c2[r], 0.f), w3v[r], s);
        const float t = s + __shfl_xor(s, 16, 64);
        if (!(g & 1)) {
            const int pl = lane >> 5;                  // 0: rows 0-7 (p0), 1: rows 8-15 (p1)
            out[(size_t)(pp * 2 + pl) * NALL + abase + col] = t + b3f[pp * 2 + pl];
        }
#else
        // ---- fallback: exchange 4 rows with partner lane, full layers 2+3 in VALU
        float f1[4], f1o[4];
        #pragma unroll
        for (int r = 0; r < 4; ++r) f1[r] = fmaxf(c1[r], 0.f);
        #pragma unroll
        for (int r = 0; r < 4; ++r) f1o[r] = __shfl_xor(f1[r], 16, 64);
        float fh[8];
        const int ob = 4 * (g & 1);
        #pragma unroll
        for (int r = 0; r < 4; ++r) { fh[ob + r] = f1[r]; fh[(ob ^ 4) + r] = f1o[r]; }
        const int pl = lane >> 5;
        const float* Pp = prm + (size_t)(pp * 2 + pl) * P_CNT;
        float s = 0.f;
        #pragma unroll
        for (int k = 0; k < 8; ++k) {
            float f2v = Pp[OB2 + k];
            #pragma unroll
            for (int h = 0; h < 8; ++h) f2v = fmaf(fh[h], Pp[OW2 + h * 8 + k], f2v);
            s = fmaf(fmaxf(f2v, 0.f), Pp[OW3 + k], s);
        }
        if (!(g & 1))
            out[(size_t)(pp * 2 + pl) * NALL + abase + col] = s + Pp[OB3];
#endif
    }
}

extern "C" void kernel_launch(void* const* d_in, const int* in_sizes, int n_in,
                              void* d_out, int out_size, void* d_ws, size_t ws_size,
                              hipStream_t stream) {
    const float* prop = (const float*)d_in[0];   // (128, 32)
    const float* allf = (const float*)d_in[1];   // (100000, 35)
    const float* W    = (const float*)d_in[2];   // (32, 369)
    const float* b    = (const float*)d_in[3];   // (369,)
    float* out = (float*)d_out;                  // (128, 100000, 1)
    char*  ws  = (char*)d_ws;

    prep_kernel<<<NPAIR, 64, 0, stream>>>(prop, W, b, ws);

    dim3 grid((NTILE + 3) / 4, 2);               // 1563 blocks x {pairs 0-31, 32-63}
    mlp_kernel<<<grid, 256, 0, stream>>>(allf, ws, out);
}

// Round 3
// 131.708 us; speedup vs baseline: 3.7567x; 1.3170x over previous
//
#include <hip/hip_runtime.h>

#define IN_C  32
#define CH    35
#define P_CNT 369
#define NPAIR 64
#define NALL  100000
#define NTILE 6250          // NALL / 16 exactly

// param offsets within a proposal's 369 floats
#define OW1 0               // w1[c][h] = c*8 + h   (c < 35)
#define OB1 280
#define OW2 288             // w2[h][k] = 288 + h*8 + k
#define OB2 352
#define OW3 360
#define OB3 368

// d_ws byte offsets
#define WS_W1F 0            // ushort [64 pair][2 kh][64 lane][8]   131072 B
#define WS_W2F 131072       // ushort [64][64 lane][4]              32768 B
#define WS_B1F 163840       // float  [64][64 lane][4]              65536 B
#define WS_B2F 229376       // float  [64][64 lane][4]              65536 B
#define WS_W3F 294912       // float  [64][64 lane][4]              65536 B
#define WS_B3F 360448       // float  [64][2]                       512 B

typedef short  bf16x8 __attribute__((ext_vector_type(8)));
typedef short  bf16x4 __attribute__((ext_vector_type(4)));
typedef float  f32x4  __attribute__((ext_vector_type(4)));

static __device__ inline unsigned short f2bf(float x) {
    union { float f; unsigned u; } v; v.f = x;
    unsigned r = v.u + 0x7FFFu + ((v.u >> 16) & 1u);   // round-to-nearest-even
    return (unsigned short)(r >> 16);
}

// ---------------- Prep: params for one pair (2 proposals) + fragment packing.
// 64 blocks x 256 threads: 4 waves share the params GEMM, wave 0 packs.
__global__ __launch_bounds__(256) void prep_kernel(
        const float* __restrict__ prop,   // (128, 32)
        const float* __restrict__ W,      // (32, 369)
        const float* __restrict__ b,      // (369,)
        char* __restrict__ ws) {
    const int pp  = blockIdx.x;           // pair index 0..63
    const int tid = threadIdx.x;
    __shared__ float P[2][P_CNT];

    // params[2pp..2pp+1][:] = prop @ W + b  (738 dots of length 32, coalesced W)
    for (int idx = tid; idx < 2 * P_CNT; idx += 256) {
        const int pl = (idx >= P_CNT) ? 1 : 0;
        const int j  = idx - pl * P_CNT;
        const float* pr = prop + (size_t)(2 * pp + pl) * IN_C;
        float acc = b[j];
        #pragma unroll
        for (int c = 0; c < IN_C; ++c)
            acc = fmaf(pr[c], W[(size_t)c * P_CNT + j], acc);
        P[pl][j] = acc;
    }
    __syncthreads();

    if (tid >= 64) return;
    const int lane = tid;
    const int g = lane >> 4;              // lane group 0..3
    const int m = lane & 15;              // M-row / N-col index within tile

    // W1F: A-fragment of 16x16x32.  A[m = h-packed][k = c]; lane: row=m, k=8g+j
    {
        unsigned short* w1f = (unsigned short*)(ws + WS_W1F);
        const int pl = m >> 3, h = m & 7;
        #pragma unroll
        for (int kh = 0; kh < 2; ++kh) {
            #pragma unroll
            for (int j = 0; j < 8; ++j) {
                const int c = kh * 32 + g * 8 + j;
                const float v = (c < CH) ? P[pl][OW1 + c * 8 + h] : 0.f;
                w1f[((size_t)(pp * 2 + kh) * 64 + lane) * 8 + j] = f2bf(v);
            }
        }
    }
    // W2F: A-fragment of 16x16x16 (block-diag packed w2). row=m, k=4g+r
    {
        unsigned short* w2f = (unsigned short*)(ws + WS_W2F);
        const int plj = m >> 3, jj = m & 7;
        #pragma unroll
        for (int r = 0; r < 4; ++r) {
            const int colh = g * 4 + r;
            const int ph = colh >> 3, h = colh & 7;
            const float v = (ph == plj) ? P[plj][OW2 + h * 8 + jj] : 0.f;
            w2f[((size_t)pp * 64 + lane) * 4 + r] = f2bf(v);
        }
    }
    // B1F / B2F / W3F: per-lane C-init rows (row = 4g + r, h/j-packed)
    {
        float* b1f = (float*)(ws + WS_B1F);
        float* b2f = (float*)(ws + WS_B2F);
        float* w3f = (float*)(ws + WS_W3F);
        #pragma unroll
        for (int r = 0; r < 4; ++r) {
            const int row = g * 4 + r;
            b1f[((size_t)pp * 64 + lane) * 4 + r] = P[row >> 3][OB1 + (row & 7)];
            b2f[((size_t)pp * 64 + lane) * 4 + r] = P[row >> 3][OB2 + (row & 7)];
            w3f[((size_t)pp * 64 + lane) * 4 + r] = P[row >> 3][OW3 + (row & 7)];
        }
    }
    if (lane < 2) ((float*)(ws + WS_B3F))[pp * 2 + lane] = P[lane][OB3];
}

// ---------------- Main: one wave per 4-tile group (64 feature rows), 16 pairs.
__global__ __launch_bounds__(256) void mlp_kernel(
        const float* __restrict__ allf,   // (100000, 35)
        const char* __restrict__ ws,
        float* __restrict__ out) {        // (128, 100000)
    const int lane = threadIdx.x & 63;
    const int wave = threadIdx.x >> 6;
    const int gidx = blockIdx.x * 4 + wave;   // tile-group index
    const int tbase = gidx * 4;
    if (tbase >= NTILE) return;
    const int g   = lane >> 4;
    const int col = lane & 15;

    // Feature B-fragments for 4 tiles (16x16x32): B[k=c][n=a]; lane: col=a, k=8g+j
    bf16x8 bf0[4], bf1[4];
    #pragma unroll
    for (int tt = 0; tt < 4; ++tt) {
        const int tile = tbase + tt;
        if (tile < NTILE) {
            const float* fr = allf + (size_t)(tile * 16 + col) * CH;
            #pragma unroll
            for (int j = 0; j < 8; ++j) {
                bf0[tt][j] = (short)f2bf(fr[g * 8 + j]);          // c = 0..31
                const int c1 = 32 + g * 8 + j;
                bf1[tt][j] = (short)(c1 < CH ? f2bf(fr[c1]) : (unsigned short)0);
            }
        } else {
            #pragma unroll
            for (int j = 0; j < 8; ++j) { bf0[tt][j] = 0; bf1[tt][j] = 0; }
        }
    }

    const bf16x8* __restrict__ w1f = (const bf16x8*)(ws + WS_W1F);
    const bf16x4* __restrict__ w2f = (const bf16x4*)(ws + WS_W2F);
    const f32x4*  __restrict__ b1f = (const f32x4*)(ws + WS_B1F);
    const f32x4*  __restrict__ b2f = (const f32x4*)(ws + WS_B2F);
    const f32x4*  __restrict__ w3f = (const f32x4*)(ws + WS_W3F);
    const float2* __restrict__ b3f = (const float2*)(ws + WS_B3F);

    const int ppbase = blockIdx.y * 16;
    #pragma unroll 1
    for (int i = 0; i < 16; ++i) {
        const int pp = ppbase + i;
        const bf16x8 w1a = w1f[(pp * 2 + 0) * 64 + lane];
        const bf16x8 w1b = w1f[(pp * 2 + 1) * 64 + lane];
        const bf16x4 w2v = w2f[pp * 64 + lane];
        const f32x4  b1v = b1f[pp * 64 + lane];
        const f32x4  b2v = b2f[pp * 64 + lane];
        const f32x4  w3v = w3f[pp * 64 + lane];
        const float2 b3v = b3f[pp];

        #pragma unroll
        for (int tt = 0; tt < 4; ++tt) {
            // ---- layer 1: C1[h-packed row, a] ; rows 4g+r in lane
            f32x4 c1 = b1v;
            c1 = __builtin_amdgcn_mfma_f32_16x16x32_bf16(w1a, bf0[tt], c1, 0, 0, 0);
            c1 = __builtin_amdgcn_mfma_f32_16x16x32_bf16(w1b, bf1[tt], c1, 0, 0, 0);

            f32x4 c2;
#if __has_builtin(__builtin_amdgcn_mfma_f32_16x16x16bf16_1k)
            // ---- layer 2: C1 output layout == 16x16x16 B-fragment layout
            bf16x4 pb;
            #pragma unroll
            for (int r = 0; r < 4; ++r) pb[r] = (short)f2bf(fmaxf(c1[r], 0.f));
            c2 = __builtin_amdgcn_mfma_f32_16x16x16bf16_1k(w2v, pb, b2v, 0, 0, 0);
#else
            // ---- fallback: redistribute rows 4g+r -> k=8g+j via shfl, use x32 MFMA
            float rl[4];
            #pragma unroll
            for (int r = 0; r < 4; ++r) rl[r] = fmaxf(c1[r], 0.f);
            bf16x8 pb8;
            #pragma unroll
            for (int j = 0; j < 8; ++j) {
                const int src = ((2 * g + (j >> 2)) << 4) + col;  // holder of row 8g+j
                pb8[j] = (short)f2bf(__shfl(rl[j & 3], src, 64));
            }
            bf16x8 w28;
            #pragma unroll
            for (int r = 0; r < 4; ++r) { w28[r] = w2v[r]; w28[r + 4] = 0; }
            // note: w2 block-diag has k = 4g+r only; upper half zero — but k=8g+j
            // spans 8g..8g+7 which for g>=2 exceeds 15 -> those A entries are 0
            // (prep wrote block-diag only for k<16); zero-pad keeps result exact.
            c2 = __builtin_amdgcn_mfma_f32_16x16x32_bf16(w28, pb8, b2v, 0, 0, 0);
#endif
            // ---- layer 3: 4-row partial dot + partner combine (xor 16)
            float s = 0.f;
            #pragma unroll
            for (int r = 0; r < 4; ++r) s = fmaf(fmaxf(c2[r], 0.f), w3v[r], s);
            const float t = s + __shfl_xor(s, 16, 64);
            if (!(g & 1) && (tbase + tt) < NTILE) {
                const int pl = lane >> 5;
                out[(size_t)(pp * 2 + pl) * NALL + (tbase + tt) * 16 + col] =
                    t + (pl ? b3v.y : b3v.x);
            }
        }
    }
}

extern "C" void kernel_launch(void* const* d_in, const int* in_sizes, int n_in,
                              void* d_out, int out_size, void* d_ws, size_t ws_size,
                              hipStream_t stream) {
    const float* prop = (const float*)d_in[0];   // (128, 32)
    const float* allf = (const float*)d_in[1];   // (100000, 35)
    const float* W    = (const float*)d_in[2];   // (32, 369)
    const float* b    = (const float*)d_in[3];   // (369,)
    float* out = (float*)d_out;                  // (128, 100000, 1)
    char*  ws  = (char*)d_ws;

    prep_kernel<<<NPAIR, 256, 0, stream>>>(prop, W, b, ws);

    // 1564 tile-groups (4 waves/block) x 4 pair-quarters
    dim3 grid(391, 4);
    mlp_kernel<<<grid, 256, 0, stream>>>(allf, ws, out);
}